// Round 19
// baseline (243.374 us; speedup 1.0000x reference)
//
#include <hip/hip_runtime.h>
#include <stdint.h>

// Problem constants (fixed by the reference)
constexpr int H_  = 2048;  // hidden
constexpr int NH_ = 16;    // heads
constexpr int HD_ = 128;   // head dim
constexpr int B_  = 2;
constexpr int T_  = 2048;
constexpr int M_  = B_ * T_;  // 4096 rows

typedef unsigned short u16;
typedef __bf16 bf16x8 __attribute__((ext_vector_type(8)));
typedef float  f32x4  __attribute__((ext_vector_type(4)));
typedef float  f32x16 __attribute__((ext_vector_type(16)));

constexpr float C1_ = 0.08838834764831845f * 1.4426950408889634f;  // scale*log2e

template <int N> struct IC { static constexpr int value = N; };

__device__ __forceinline__ u16 f2bf(float f) {
  uint32_t u = __builtin_bit_cast(uint32_t, f);
  u += 0x7fffu + ((u >> 16) & 1u);   // round-to-nearest-even
  return (u16)(u >> 16);
}

// packed f32x2 -> bf16x2 (RNE), T12: no builtin on gfx950, inline asm
__device__ __forceinline__ uint32_t cvtpk(float lo, float hi) {
  uint32_t r;
  asm("v_cvt_pk_bf16_f32 %0, %1, %2" : "=v"(r) : "v"(lo), "v"(hi));
  return r;
}

// global -> LDS direct DMA, 16B per lane. LDS dest must be the WAVE-UNIFORM
// base (HW adds lane*16); global src is per-lane.
__device__ __forceinline__ void gload_lds16(const void* g, void* lds) {
  auto gp = (const __attribute__((address_space(1))) uint32_t*)(uintptr_t)g;
  auto lp = (__attribute__((address_space(3))) uint32_t*)(uint32_t)(uintptr_t)lds;
  __builtin_amdgcn_global_load_lds(gp, lp, 16, 0, 0);
}

__device__ __forceinline__ f32x4 mfma16(bf16x8 a, bf16x8 b, f32x4 c) {
  return __builtin_amdgcn_mfma_f32_16x16x32_bf16(a, b, c, 0, 0, 0);
}
__device__ __forceinline__ f32x16 mfma32(bf16x8 a, bf16x8 b, f32x16 c) {
  return __builtin_amdgcn_mfma_f32_32x32x16_bf16(a, b, c, 0, 0, 0);
}

// ------------------------------------------------------- fused fp32->bf16 x5
__global__ __launch_bounds__(512) void cvt5_kernel(
    const float4* __restrict__ x,  const float4* __restrict__ wq,
    const float4* __restrict__ wk, const float4* __restrict__ wv,
    const float4* __restrict__ wo, ushort4* __restrict__ dst) {
  const int bid = blockIdx.x, tid = threadIdx.x;
  const float4* src;
  size_t idx, dof;
  if (bid < 4096) {                         // x: 2,097,152 float4
    src = x; idx = (size_t)bid * 512 + tid; dof = 0;
  } else {                                  // weights: 1,048,576 float4 each
    int w = (bid - 4096) >> 11;
    int r = (bid - 4096) & 2047;
    idx = (size_t)r * 512 + tid;
    dof = 2097152u + (size_t)w * 1048576u;
    src = (w == 0) ? wq : (w == 1) ? wk : (w == 2) ? wv : wo;
  }
  float4 v = src[idx];
  ushort4 o;
  o.x = f2bf(v.x); o.y = f2bf(v.y); o.z = f2bf(v.z); o.w = f2bf(v.w);
  dst[dof + idx] = o;
}

// --------------------------- GEMM 256x128, 32x32 MFMA, 2-phase, TRIPLE buffer
// R18->R19: inner loop swapped to v_mfma_f32_32x32x16_bf16. Per wave 64x64 =
// 2x2 frags of 32x32 (f32x16 acc). Per K-tile: 2 phases x 8 MFMA (was 4 x 8
// 16x16) -> half the MFMA issue slots, half the barriers. Staging, triple
// buffer, counted-vmcnt(6), lgkmcnt(0) race fix: unchanged from R18.
// Fragment maps (HW-verified m74/m101): A/B row|col = lane&31, k-half =
// lane>>5 (8 contiguous k each); C/D col = lane&31, row = (reg&3) +
// 8*(reg>>2) + 4*(lane>>5).
__device__ __forceinline__ void gemm256_core(const u16* __restrict__ A,
                                             const u16* __restrict__ Bm,
                                             const float* __restrict__ bias,
                                             void* __restrict__ Cout,
                                             int bid, int outmode,
                                             float oscale) {
  __shared__ u16 As[3][256 * 64];   // 96 KB
  __shared__ u16 Bs[3][128 * 64];   // 48 KB
  constexpr int Kg = H_;
  constexpr int NT = Kg / 64;               // 32
  const int tid = threadIdx.x;
  const int wave = tid >> 6, lane = tid & 63;
  const int l31 = lane & 31, lhi5 = lane >> 5;
  const int tm = bid & 15, tn = bid >> 4;   // 16 x 16 = 256 blocks
  const int m0 = tm << 8, n0 = tn << 7;
  const int wr = wave >> 1, wc = wave & 1;

  f32x16 acc[2][2] = {};

  // ---- hoisted staging state: per-thread global pointers (invariant part)
  const u16* pA[4];
  const u16* pB[2];
  {
    int o = tid * 16;
    int row = o >> 7;
    int sw  = o ^ ((row & 7) << 4);
    int c8  = (sw >> 4) & 7;
#pragma unroll
    for (int a = 0; a < 4; ++a)
      pA[a] = A + (size_t)(m0 + a * 64 + row) * Kg + c8 * 8;
#pragma unroll
    for (int a = 0; a < 2; ++a)
      pB[a] = Bm + (size_t)(n0 + a * 64 + row) * Kg + c8 * 8;
  }
  const int ldsoff = wave * 1024;

  // ---- hoisted swizzled ds_read offsets for 32x32 fragments
  // rdA(ks, mi): row = wr*64 + mi*32 + l31, 16B at k = ks*16 + lhi5*8
  int obA[4][2], obB[4][2];
#pragma unroll
  for (int ks = 0; ks < 4; ++ks) {
#pragma unroll
    for (int i = 0; i < 2; ++i) {
      int rowA = wr * 64 + i * 32 + l31;
      obA[ks][i] = (rowA * 128 + ks * 32 + lhi5 * 16) ^ ((rowA & 7) << 4);
      int rowB = wc * 64 + i * 32 + l31;
      obB[ks][i] = (rowB * 128 + ks * 32 + lhi5 * 16) ^ ((rowB & 7) << 4);
    }
  }

  auto stageA = [&](int kt, auto bufc, int a) {
    constexpr int BUF = decltype(bufc)::value;
    gload_lds16(pA[a] + kt * 64,
                (char*)&As[BUF][0] + a * 8192 + ldsoff);
  };
  auto stageB = [&](int kt, auto bufc, int a) {
    constexpr int BUF = decltype(bufc)::value;
    gload_lds16(pB[a] + kt * 64,
                (char*)&Bs[BUF][0] + a * 8192 + ldsoff);
  };

  // prologue: stage tiles 0 (buf0) and 1 (buf1); wait tile 0 (6 in flight)
  stageB(0, IC<0>{}, 0); stageB(0, IC<0>{}, 1);
  stageA(0, IC<0>{}, 0); stageA(0, IC<0>{}, 1);
  stageA(0, IC<0>{}, 2); stageA(0, IC<0>{}, 3);
  stageB(1, IC<1>{}, 0); stageB(1, IC<1>{}, 1);
  stageA(1, IC<1>{}, 0); stageA(1, IC<1>{}, 1);
  stageA(1, IC<1>{}, 2); stageA(1, IC<1>{}, 3);
  asm volatile("s_waitcnt vmcnt(6)" ::: "memory");
  __builtin_amdgcn_s_barrier();
  asm volatile("" ::: "memory");

  auto tile = [&](int kt, auto bufc) {
    constexpr int BUF = decltype(bufc)::value;
    constexpr int NXT = (BUF + 2) % 3;
    const bool hn2 = (kt + 2 < NT);
    const char* Ab = (const char*)&As[BUF][0];
    const char* Bb = (const char*)&Bs[BUF][0];
    bf16x8 a00, a01, a10, a11, b00, b01, b10, b11;

    // ---- phase 0: ksteps 0,1; stage 3 of kt+2's loads
    a00 = *(const bf16x8*)(Ab + obA[0][0]); a01 = *(const bf16x8*)(Ab + obA[0][1]);
    b00 = *(const bf16x8*)(Bb + obB[0][0]); b01 = *(const bf16x8*)(Bb + obB[0][1]);
    a10 = *(const bf16x8*)(Ab + obA[1][0]); a11 = *(const bf16x8*)(Ab + obA[1][1]);
    b10 = *(const bf16x8*)(Bb + obB[1][0]); b11 = *(const bf16x8*)(Bb + obB[1][1]);
    if (hn2) {
      stageB(kt + 2, IC<NXT>{}, 0); stageB(kt + 2, IC<NXT>{}, 1);
      stageA(kt + 2, IC<NXT>{}, 0);
    }
    __builtin_amdgcn_s_barrier(); asm volatile("" ::: "memory");
    __builtin_amdgcn_s_setprio(1);
    acc[0][0] = mfma32(a00, b00, acc[0][0]); acc[0][1] = mfma32(a00, b01, acc[0][1]);
    acc[1][0] = mfma32(a01, b00, acc[1][0]); acc[1][1] = mfma32(a01, b01, acc[1][1]);
    acc[0][0] = mfma32(a10, b10, acc[0][0]); acc[0][1] = mfma32(a10, b11, acc[0][1]);
    acc[1][0] = mfma32(a11, b10, acc[1][0]); acc[1][1] = mfma32(a11, b11, acc[1][1]);
    __builtin_amdgcn_s_setprio(0);
    __builtin_amdgcn_s_barrier(); asm volatile("" ::: "memory");

    // ---- phase 1: ksteps 2,3; stage remaining 3; boundary counted wait
    a00 = *(const bf16x8*)(Ab + obA[2][0]); a01 = *(const bf16x8*)(Ab + obA[2][1]);
    b00 = *(const bf16x8*)(Bb + obB[2][0]); b01 = *(const bf16x8*)(Bb + obB[2][1]);
    a10 = *(const bf16x8*)(Ab + obA[3][0]); a11 = *(const bf16x8*)(Ab + obA[3][1]);
    b10 = *(const bf16x8*)(Bb + obB[3][0]); b11 = *(const bf16x8*)(Bb + obB[3][1]);
    if (hn2) {
      stageA(kt + 2, IC<NXT>{}, 1); stageA(kt + 2, IC<NXT>{}, 2);
      stageA(kt + 2, IC<NXT>{}, 3);
    }
    __builtin_amdgcn_s_barrier(); asm volatile("" ::: "memory");
    __builtin_amdgcn_s_setprio(1);
    acc[0][0] = mfma32(a00, b00, acc[0][0]); acc[0][1] = mfma32(a00, b01, acc[0][1]);
    acc[1][0] = mfma32(a01, b00, acc[1][0]); acc[1][1] = mfma32(a01, b01, acc[1][1]);
    acc[0][0] = mfma32(a10, b10, acc[0][0]); acc[0][1] = mfma32(a10, b11, acc[0][1]);
    acc[1][0] = mfma32(a11, b10, acc[1][0]); acc[1][1] = mfma32(a11, b11, acc[1][1]);
    __builtin_amdgcn_s_setprio(0);
    // RACE FIX: lgkmcnt(0) pins all LDS reads retired before the release
    // barrier (next tile DMA-overwrites a rotated buffer).
    if (hn2)
      asm volatile("s_waitcnt vmcnt(6) lgkmcnt(0)" ::: "memory");
    else
      asm volatile("s_waitcnt vmcnt(0) lgkmcnt(0)" ::: "memory");
    __builtin_amdgcn_s_barrier(); asm volatile("" ::: "memory");
  };

#pragma unroll 1
  for (int kt = 0; kt < 30; kt += 3) {
    tile(kt,     IC<0>{});
    tile(kt + 1, IC<1>{});
    tile(kt + 2, IC<2>{});
  }
  tile(30, IC<0>{});
  tile(31, IC<1>{});

  // ---- epilogue: 32x32 C/D map: col = l31, row = (reg&3)+8*(reg>>2)+4*lhi5
  float bv[2];
#pragma unroll
  for (int ni = 0; ni < 2; ++ni) bv[ni] = bias[n0 + wc * 64 + ni * 32 + l31];

  if (outmode == 2) {
    // V^T: (m,n) -> Vt[(b*2048 + n) * T + t], b = m>>11, t = m&2047.
    // regs 4g..4g+3 are t-contiguous -> one ushort4 per (frag, g).
    const int b = m0 >> 11;
#pragma unroll
    for (int mi = 0; mi < 2; ++mi) {
#pragma unroll
      for (int ni = 0; ni < 2; ++ni) {
        int n = n0 + wc * 64 + ni * 32 + l31;
#pragma unroll
        for (int g = 0; g < 4; ++g) {
          int t = (m0 & 2047) + wr * 64 + mi * 32 + g * 8 + lhi5 * 4;
          ushort4 pk;
          pk.x = f2bf(acc[mi][ni][g * 4 + 0] + bv[ni]);
          pk.y = f2bf(acc[mi][ni][g * 4 + 1] + bv[ni]);
          pk.z = f2bf(acc[mi][ni][g * 4 + 2] + bv[ni]);
          pk.w = f2bf(acc[mi][ni][g * 4 + 3] + bv[ni]);
          *(ushort4*)((u16*)Cout + (size_t)(b * 2048 + n) * T_ + t) = pk;
        }
      }
    }
  } else {
#pragma unroll
    for (int mi = 0; mi < 2; ++mi) {
#pragma unroll
      for (int ni = 0; ni < 2; ++ni) {
        int n = n0 + wc * 64 + ni * 32 + l31;
#pragma unroll
        for (int g = 0; g < 4; ++g) {
#pragma unroll
          for (int j = 0; j < 4; ++j) {
            int m = m0 + wr * 64 + mi * 32 + g * 8 + lhi5 * 4 + j;
            float v = (acc[mi][ni][g * 4 + j] + bv[ni]) * oscale;
            if (outmode == 1)
              ((float*)Cout)[(size_t)m * H_ + n] = v;
            else
              ((u16*)Cout)[(size_t)m * H_ + n] = f2bf(v);
          }
        }
      }
    }
  }
}

template <int OUTMODE>
__global__ __launch_bounds__(512, 1) void gemm256_bt_k(
    const u16* __restrict__ A, const u16* __restrict__ Bm,
    const float* __restrict__ bias, void* __restrict__ Cout, float oscale) {
  gemm256_core(A, Bm, bias, Cout, blockIdx.x, OUTMODE, oscale);
}

// ------------------------------------------------------------ flash attention
// (R18 proven: dual-state single staging stream + lgkmcnt(0) race fix.)
__global__ __launch_bounds__(256, 2) void attn_kernel(
    const u16* __restrict__ Q, const u16* __restrict__ K,
    const u16* __restrict__ Vt, u16* __restrict__ ctx) {
  __shared__ u16 Ks[2][64 * 128];    // [key][d], 256B rows, swizzled
  __shared__ u16 Vs[2][128 * 64];    // [d][key], 128B rows, swizzled
  __shared__ u16 Ps[4][1024];        // per-wave P^T, swizzled [slot][q][8]

  const int tid = threadIdx.x, wave = tid >> 6, lane = tid & 63;
  const int l15 = lane & 15, lhi = lane >> 4;

  const int bid = blockIdx.x;
  const int xcd = bid & 7, idx = bid >> 3;
  const int bh = xcd * 4 + (idx & 3);       // 4 (b,h) pairs per XCD
  const int qj = idx >> 2;                  // 0..15
  const int qi = (qj < 8) ? qj : 23 - qj;   // complement remap
  const int b = bh >> 4, h = bh & 15;
  const int qb0 = qi, qb1 = 31 - qi;        // qb0 < qb1 always

  const float THR = 11.5f;                  // 8 nats in log2 units
  const float NI  = -__builtin_inff();

  auto stage = [&](auto bufc, int kv0) {
    constexpr int BUF = decltype(bufc)::value;
#pragma unroll
    for (int is = 0; is < 4; ++is) {
      {  // K tile: 64 rows x 256B
        int o_ = is * 4096 + tid * 16;
        int row = o_ >> 8;
        int sw = o_ ^ (((o_ >> 8) & 7) << 4);
        int c8 = (sw >> 4) & 15;
        gload_lds16(K + (size_t)(b * T_ + kv0 + row) * H_ + h * HD_ + c8 * 8,
                    &Ks[BUF][0] + (is * 2048 + wave * 512));
      }
      {  // Vt tile: 128 rows x 128B
        int o_ = is * 4096 + tid * 16;
        int row = o_ >> 7;
        int sw = o_ ^ (((o_ >> 7) & 7) << 4);
        int t8 = (sw >> 4) & 7;
        gload_lds16(Vt + (size_t)(bh * HD_ + row) * T_ + kv0 + t8 * 8,
                    &Vs[BUF][0] + (is * 4096 / 2 + wave * 512));
      }
    }
  };

  // preload both q-tiles' fragments (prologue vmcnt(0) covers them)
  bf16x8 qc0[4], qc1[4];
  {
    const u16* q0p =
        Q + (size_t)(b * T_ + qb0 * 64 + wave * 16 + l15) * H_ + h * HD_ + lhi * 8;
    const u16* q1p =
        Q + (size_t)(b * T_ + qb1 * 64 + wave * 16 + l15) * H_ + h * HD_ + lhi * 8;
#pragma unroll
    for (int kk = 0; kk < 4; ++kk) {
      qc0[kk] = *(const bf16x8*)(q0p + kk * 32);
      qc1[kk] = *(const bf16x8*)(q1p + kk * 32);
    }
  }

  f32x4 o0[8] = {}, o1[8] = {};
  float m20 = NI, lr0 = 0.f, m21 = NI, lr1 = 0.f;

  auto comp = [&](f32x4 (&o)[8], float& m2, float& lr, bf16x8 (&qf)[4],
                  int q0, bool diag, int kv0, auto bufc) {
    constexpr int BUF = decltype(bufc)::value;
    const int qrow = q0 + l15;

    f32x4 sv[4];
    __builtin_amdgcn_s_setprio(1);
#pragma unroll
    for (int kt = 0; kt < 4; ++kt) {
      f32x4 sacc = {0.f, 0.f, 0.f, 0.f};
#pragma unroll
      for (int kk = 0; kk < 4; ++kk) {
        int row = kt * 16 + l15;
        int ob = (row * 256 + kk * 64 + lhi * 16) ^ ((row & 7) << 4);
        bf16x8 kf = *(const bf16x8*)((const char*)&Ks[BUF][0] + ob);
        sacc = mfma16(kf, qf[kk], sacc);
      }
      sv[kt] = sacc;
    }
    __builtin_amdgcn_s_setprio(0);

    float pmax2;
    {
      float pm[4];
      if (diag) {
#pragma unroll
        for (int kt = 0; kt < 4; ++kt) {
          int key0 = kv0 + kt * 16 + lhi * 4;
#pragma unroll
          for (int r = 0; r < 4; ++r)
            sv[kt][r] = (key0 + r <= qrow) ? sv[kt][r] : NI;
          pm[kt] = fmaxf(fmaxf(sv[kt][0], sv[kt][1]),
                         fmaxf(sv[kt][2], sv[kt][3]));
        }
      } else {
#pragma unroll
        for (int kt = 0; kt < 4; ++kt)
          pm[kt] = fmaxf(fmaxf(sv[kt][0], sv[kt][1]),
                         fmaxf(sv[kt][2], sv[kt][3]));
      }
      pmax2 = fmaxf(fmaxf(pm[0], pm[1]), fmaxf(pm[2], pm[3]));
    }
    pmax2 = fmaxf(pmax2, __shfl_xor(pmax2, 16));
    pmax2 = fmaxf(pmax2, __shfl_xor(pmax2, 32));

    if (__any(pmax2 - m2 > THR)) {
      float mn = fmaxf(m2, pmax2);
      float al = exp2f(m2 - mn);
      m2 = mn;
      lr *= al;
      float alo[4];
#pragma unroll
      for (int r = 0; r < 4; ++r) alo[r] = __shfl(al, lhi * 4 + r);
#pragma unroll
      for (int dt = 0; dt < 8; ++dt)
#pragma unroll
        for (int r = 0; r < 4; ++r) o[dt][r] *= alo[r];
    }

    float rsk[4];
#pragma unroll
    for (int kt = 0; kt < 4; ++kt) {
#pragma unroll
      for (int r = 0; r < 4; ++r) sv[kt][r] = exp2f(sv[kt][r] - m2);
      rsk[kt] = (sv[kt][0] + sv[kt][1]) + (sv[kt][2] + sv[kt][3]);
    }
    float rs = (rsk[0] + rsk[1]) + (rsk[2] + rsk[3]);
    rs += __shfl_xor(rs, 16);
    rs += __shfl_xor(rs, 32);
    lr += rs;

#pragma unroll
    for (int kt = 0; kt < 4; ++kt) {
      int slot = kt * 2 + (lhi >> 1);
      uint2 pk;
      pk.x = cvtpk(sv[kt][0], sv[kt][1]);
      pk.y = cvtpk(sv[kt][2], sv[kt][3]);
      *(uint2*)&Ps[wave][slot * 128 + ((l15 * 8) ^ ((slot & 7) << 3)) +
                         (lhi & 1) * 4] = pk;
    }
    asm volatile("" ::: "memory");

    __builtin_amdgcn_s_setprio(1);
#pragma unroll
    for (int ks = 0; ks < 2; ++ks) {
      int slot = ks * 4 + lhi;
      bf16x8 pf = *(const bf16x8*)&Ps[wave][slot * 128 +
                                            ((l15 * 8) ^ ((slot & 7) << 3))];
#pragma unroll
      for (int dt = 0; dt < 8; ++dt) {
        int row = dt * 16 + l15;
        int ob = (row * 128 + ks * 64 + lhi * 16) ^ ((row & 7) << 4);
        bf16x8 vf = *(const bf16x8*)((const char*)&Vs[BUF][0] + ob);
        o[dt] = mfma16(pf, vf, o[dt]);
      }
    }
    __builtin_amdgcn_s_setprio(0);
    asm volatile("" ::: "memory");
  };

  auto flushout = [&](f32x4 (&o)[8], float lr, int qtile) {
    float invo[4];
    float inv = 1.0f / lr;
#pragma unroll
    for (int r = 0; r < 4; ++r) invo[r] = __shfl(inv, lhi * 4 + r);
    int q0 = qtile * 64 + wave * 16;
#pragma unroll
    for (int dt = 0; dt < 8; ++dt)
#pragma unroll
      for (int r = 0; r < 4; ++r)
        ctx[(size_t)(b * T_ + q0 + lhi * 4 + r) * H_ + h * HD_ + dt * 16 +
            l15] = f2bf(o[dt][r] * invo[r]);
  };

  stage(IC<0>{}, 0);
  asm volatile("s_waitcnt vmcnt(0)" ::: "memory");
  __builtin_amdgcn_s_barrier();
  asm volatile("" ::: "memory");

  auto body = [&](int t, auto bufc) {
    constexpr int BUF = decltype(bufc)::value;
    if (t < qb1) stage(IC<BUF ^ 1>{}, (t + 1) * 64);
    if (t < qb1)
      asm volatile("s_waitcnt vmcnt(8)" ::: "memory");
    else
      asm volatile("s_waitcnt vmcnt(0)" ::: "memory");
    __builtin_amdgcn_s_barrier();
    asm volatile("" ::: "memory");

    const int kv0 = t * 64;
    comp(o1, m21, lr1, qc1, qb1 * 64 + wave * 16, t == qb1, kv0, bufc);
    if (t <= qb0)
      comp(o0, m20, lr0, qc0, qb0 * 64 + wave * 16, t == qb0, kv0, bufc);

    // RACE FIX: pin all LDS reads of buffer BUF retired before the release
    // barrier (next body's stage DMAs overwrite BUF).
    asm volatile("s_waitcnt lgkmcnt(0)" ::: "memory");
    __builtin_amdgcn_s_barrier();
    asm volatile("" ::: "memory");
  };

#pragma unroll 1
  for (int t2 = 0; t2 + 1 <= qb1; t2 += 2) {
    body(t2, IC<0>{});
    body(t2 + 1, IC<1>{});
  }
  if ((qb1 & 1) == 0) body(qb1, IC<0>{});

  flushout(o0, lr0, qb0);
  flushout(o1, lr1, qb1);
}

// ------------------------------------------------------------------- launcher
extern "C" void kernel_launch(void* const* d_in, const int* in_sizes, int n_in,
                              void* d_out, int out_size, void* d_ws,
                              size_t ws_size, hipStream_t stream) {
  const float* x  = (const float*)d_in[0];
  const float* wq = (const float*)d_in[1];
  const float* bq = (const float*)d_in[2];
  const float* wk = (const float*)d_in[3];
  const float* bk = (const float*)d_in[4];
  const float* wv = (const float*)d_in[5];
  const float* bv = (const float*)d_in[6];
  const float* wo = (const float*)d_in[7];
  const float* bo = (const float*)d_in[8];

  char* ws = (char*)d_ws;
  constexpr size_t SZ_X = (size_t)M_ * H_ * 2;  // 16.8 MB (bf16 activation)
  constexpr size_t SZ_W = (size_t)H_ * H_ * 2;  // 8.4 MB (bf16 weight)
  u16* xb  = (u16*)(ws);
  u16* wqb = (u16*)(ws + SZ_X);
  u16* wkb = (u16*)(ws + SZ_X + 1 * SZ_W);
  u16* wvb = (u16*)(ws + SZ_X + 2 * SZ_W);
  u16* wob = (u16*)(ws + SZ_X + 3 * SZ_W);
  u16* Qb  = (u16*)(ws + 1 * SZ_X + 4 * SZ_W);
  u16* Kb  = (u16*)(ws + 2 * SZ_X + 4 * SZ_W);
  u16* Vtb = (u16*)(ws + 3 * SZ_X + 4 * SZ_W);  // V^T written by gemm256<2>
  u16* ctx = xb;  // xb is dead after the QKV GEMMs

  // fused fp32->bf16: x + 4 weights, one dispatch (dsts contiguous in ws)
  cvt5_kernel<<<12288, 512, 0, stream>>>((const float4*)x, (const float4*)wq,
                                         (const float4*)wk, (const float4*)wv,
                                         (const float4*)wo, (ushort4*)ws);

  // QKV projections: 256x128-tile 2-phase 32x32-MFMA triple-buffered GEMMs.
  // Q pre-scaled by C1_ (attn consumes log2-domain scores).
  gemm256_bt_k<0><<<256, 512, 0, stream>>>(xb, wqb, bq, Qb, C1_);
  gemm256_bt_k<0><<<256, 512, 0, stream>>>(xb, wkb, bk, Kb, 1.0f);
  gemm256_bt_k<2><<<256, 512, 0, stream>>>(xb, wvb, bv, Vtb, 1.0f);

  // dual-state paired causal flash attention: 512 blocks x 256 threads
  attn_kernel<<<512, 256, 0, stream>>>(Qb, Kb, Vtb, ctx);

  gemm256_bt_k<1><<<256, 512, 0, stream>>>(ctx, wob, bo, d_out, 1.0f);
}

// Round 20
// 225.974 us; speedup vs baseline: 1.0770x; 1.0770x over previous
//
#include <hip/hip_runtime.h>
#include <stdint.h>

// Problem constants (fixed by the reference)
constexpr int H_  = 2048;  // hidden
constexpr int NH_ = 16;    // heads
constexpr int HD_ = 128;   // head dim
constexpr int B_  = 2;
constexpr int T_  = 2048;
constexpr int M_  = B_ * T_;  // 4096 rows

typedef unsigned short u16;
typedef __bf16 bf16x8 __attribute__((ext_vector_type(8)));
typedef float  f32x4  __attribute__((ext_vector_type(4)));

constexpr float C1_ = 0.08838834764831845f * 1.4426950408889634f;  // scale*log2e

template <int N> struct IC { static constexpr int value = N; };

__device__ __forceinline__ u16 f2bf(float f) {
  uint32_t u = __builtin_bit_cast(uint32_t, f);
  u += 0x7fffu + ((u >> 16) & 1u);   // round-to-nearest-even
  return (u16)(u >> 16);
}

// packed f32x2 -> bf16x2 (RNE), T12: no builtin on gfx950, inline asm
__device__ __forceinline__ uint32_t cvtpk(float lo, float hi) {
  uint32_t r;
  asm("v_cvt_pk_bf16_f32 %0, %1, %2" : "=v"(r) : "v"(lo), "v"(hi));
  return r;
}

// global -> LDS direct DMA, 16B per lane. LDS dest must be the WAVE-UNIFORM
// base (HW adds lane*16); global src is per-lane.
__device__ __forceinline__ void gload_lds16(const void* g, void* lds) {
  auto gp = (const __attribute__((address_space(1))) uint32_t*)(uintptr_t)g;
  auto lp = (__attribute__((address_space(3))) uint32_t*)(uint32_t)(uintptr_t)lds;
  __builtin_amdgcn_global_load_lds(gp, lp, 16, 0, 0);
}

__device__ __forceinline__ f32x4 mfma16(bf16x8 a, bf16x8 b, f32x4 c) {
  return __builtin_amdgcn_mfma_f32_16x16x32_bf16(a, b, c, 0, 0, 0);
}

// ------------------------------------------------------- fused fp32->bf16 x5
__global__ __launch_bounds__(512) void cvt5_kernel(
    const float4* __restrict__ x,  const float4* __restrict__ wq,
    const float4* __restrict__ wk, const float4* __restrict__ wv,
    const float4* __restrict__ wo, ushort4* __restrict__ dst) {
  const int bid = blockIdx.x, tid = threadIdx.x;
  const float4* src;
  size_t idx, dof;
  if (bid < 4096) {                         // x: 2,097,152 float4
    src = x; idx = (size_t)bid * 512 + tid; dof = 0;
  } else {                                  // weights: 1,048,576 float4 each
    int w = (bid - 4096) >> 11;
    int r = (bid - 4096) & 2047;
    idx = (size_t)r * 512 + tid;
    dof = 2097152u + (size_t)w * 1048576u;
    src = (w == 0) ? wq : (w == 1) ? wk : (w == 2) ? wv : wo;
  }
  float4 v = src[idx];
  ushort4 o;
  o.x = f2bf(v.x); o.y = f2bf(v.y); o.z = f2bf(v.z); o.w = f2bf(v.w);
  dst[dof + idx] = o;
}

// ------------------------------------- GEMM 256x128, 4-phase, TRIPLE buffer
// R18 final: VALU-diet (hoisted pointers/offsets), counted-vmcnt(6),
// lgkmcnt(0) race fix at the release barrier. 16x16x32 MFMA (R19's 32x32
// swap regressed: VGPR pressure + longer blocking chains).
__device__ __forceinline__ void gemm256_core(const u16* __restrict__ A,
                                             const u16* __restrict__ Bm,
                                             const float* __restrict__ bias,
                                             void* __restrict__ Cout,
                                             int bid, int outmode,
                                             float oscale) {
  __shared__ u16 As[3][256 * 64];   // 96 KB
  __shared__ u16 Bs[3][128 * 64];   // 48 KB
  constexpr int Kg = H_;
  constexpr int NT = Kg / 64;               // 32
  const int tid = threadIdx.x;
  const int wave = tid >> 6, lane = tid & 63, l15 = lane & 15, lhi = lane >> 4;
  const int tm = bid & 15, tn = bid >> 4;   // 16 x 16 = 256 blocks
  const int m0 = tm << 8, n0 = tn << 7;
  const int wr = wave >> 1, wc = wave & 1;

  f32x4 acc[4][4] = {};

  const u16* pA[4];
  const u16* pB[2];
  {
    int o = tid * 16;
    int row = o >> 7;
    int sw  = o ^ ((row & 7) << 4);
    int c8  = (sw >> 4) & 7;
#pragma unroll
    for (int a = 0; a < 4; ++a)
      pA[a] = A + (size_t)(m0 + a * 64 + row) * Kg + c8 * 8;
#pragma unroll
    for (int a = 0; a < 2; ++a)
      pB[a] = Bm + (size_t)(n0 + a * 64 + row) * Kg + c8 * 8;
  }
  const int ldsoff = wave * 1024;

  int obA[2][4], obB[2][4];
#pragma unroll
  for (int kk = 0; kk < 2; ++kk) {
#pragma unroll
    for (int mi = 0; mi < 4; ++mi) {
      int rowA = wr * 64 + mi * 16 + l15;
      obA[kk][mi] = (rowA * 128 + kk * 64 + lhi * 16) ^ ((rowA & 7) << 4);
      int rowB = wc * 64 + mi * 16 + l15;
      obB[kk][mi] = (rowB * 128 + kk * 64 + lhi * 16) ^ ((rowB & 7) << 4);
    }
  }

  auto stageA = [&](int kt, auto bufc, int a) {
    constexpr int BUF = decltype(bufc)::value;
    gload_lds16(pA[a] + kt * 64,
                (char*)&As[BUF][0] + a * 8192 + ldsoff);
  };
  auto stageB = [&](int kt, auto bufc, int a) {
    constexpr int BUF = decltype(bufc)::value;
    gload_lds16(pB[a] + kt * 64,
                (char*)&Bs[BUF][0] + a * 8192 + ldsoff);
  };

  stageB(0, IC<0>{}, 0); stageB(0, IC<0>{}, 1);
  stageA(0, IC<0>{}, 0); stageA(0, IC<0>{}, 1);
  stageA(0, IC<0>{}, 2); stageA(0, IC<0>{}, 3);
  stageB(1, IC<1>{}, 0); stageB(1, IC<1>{}, 1);
  stageA(1, IC<1>{}, 0); stageA(1, IC<1>{}, 1);
  stageA(1, IC<1>{}, 2); stageA(1, IC<1>{}, 3);
  asm volatile("s_waitcnt vmcnt(6)" ::: "memory");
  __builtin_amdgcn_s_barrier();
  asm volatile("" ::: "memory");

  auto tile = [&](int kt, auto bufc) {
    constexpr int BUF = decltype(bufc)::value;
    constexpr int NXT = (BUF + 2) % 3;
    const bool hn2 = (kt + 2 < NT);
    const char* Ab = (const char*)&As[BUF][0];
    const char* Bb = (const char*)&Bs[BUF][0];
    bf16x8 a0, a1, b0, b1, b2, b3;

    a0 = *(const bf16x8*)(Ab + obA[0][0]); a1 = *(const bf16x8*)(Ab + obA[0][1]);
    b0 = *(const bf16x8*)(Bb + obB[0][0]); b1 = *(const bf16x8*)(Bb + obB[0][1]);
    b2 = *(const bf16x8*)(Bb + obB[0][2]); b3 = *(const bf16x8*)(Bb + obB[0][3]);
    if (hn2) { stageB(kt + 2, IC<NXT>{}, 0); stageB(kt + 2, IC<NXT>{}, 1); }
    __builtin_amdgcn_s_barrier(); asm volatile("" ::: "memory");
    __builtin_amdgcn_s_setprio(1);
    acc[0][0] = mfma16(a0, b0, acc[0][0]); acc[0][1] = mfma16(a0, b1, acc[0][1]);
    acc[0][2] = mfma16(a0, b2, acc[0][2]); acc[0][3] = mfma16(a0, b3, acc[0][3]);
    acc[1][0] = mfma16(a1, b0, acc[1][0]); acc[1][1] = mfma16(a1, b1, acc[1][1]);
    acc[1][2] = mfma16(a1, b2, acc[1][2]); acc[1][3] = mfma16(a1, b3, acc[1][3]);
    __builtin_amdgcn_s_setprio(0);
    __builtin_amdgcn_s_barrier(); asm volatile("" ::: "memory");

    a0 = *(const bf16x8*)(Ab + obA[0][2]); a1 = *(const bf16x8*)(Ab + obA[0][3]);
    if (hn2) { stageA(kt + 2, IC<NXT>{}, 0); stageA(kt + 2, IC<NXT>{}, 1); }
    __builtin_amdgcn_s_barrier(); asm volatile("" ::: "memory");
    __builtin_amdgcn_s_setprio(1);
    acc[2][0] = mfma16(a0, b0, acc[2][0]); acc[2][1] = mfma16(a0, b1, acc[2][1]);
    acc[2][2] = mfma16(a0, b2, acc[2][2]); acc[2][3] = mfma16(a0, b3, acc[2][3]);
    acc[3][0] = mfma16(a1, b0, acc[3][0]); acc[3][1] = mfma16(a1, b1, acc[3][1]);
    acc[3][2] = mfma16(a1, b2, acc[3][2]); acc[3][3] = mfma16(a1, b3, acc[3][3]);
    __builtin_amdgcn_s_setprio(0);
    __builtin_amdgcn_s_barrier(); asm volatile("" ::: "memory");

    a0 = *(const bf16x8*)(Ab + obA[1][0]); a1 = *(const bf16x8*)(Ab + obA[1][1]);
    b0 = *(const bf16x8*)(Bb + obB[1][0]); b1 = *(const bf16x8*)(Bb + obB[1][1]);
    b2 = *(const bf16x8*)(Bb + obB[1][2]); b3 = *(const bf16x8*)(Bb + obB[1][3]);
    if (hn2) { stageA(kt + 2, IC<NXT>{}, 2); stageA(kt + 2, IC<NXT>{}, 3); }
    __builtin_amdgcn_s_barrier(); asm volatile("" ::: "memory");
    __builtin_amdgcn_s_setprio(1);
    acc[0][0] = mfma16(a0, b0, acc[0][0]); acc[0][1] = mfma16(a0, b1, acc[0][1]);
    acc[0][2] = mfma16(a0, b2, acc[0][2]); acc[0][3] = mfma16(a0, b3, acc[0][3]);
    acc[1][0] = mfma16(a1, b0, acc[1][0]); acc[1][1] = mfma16(a1, b1, acc[1][1]);
    acc[1][2] = mfma16(a1, b2, acc[1][2]); acc[1][3] = mfma16(a1, b3, acc[1][3]);
    __builtin_amdgcn_s_setprio(0);
    __builtin_amdgcn_s_barrier(); asm volatile("" ::: "memory");

    a0 = *(const bf16x8*)(Ab + obA[1][2]); a1 = *(const bf16x8*)(Ab + obA[1][3]);
    __builtin_amdgcn_s_barrier(); asm volatile("" ::: "memory");
    __builtin_amdgcn_s_setprio(1);
    acc[2][0] = mfma16(a0, b0, acc[2][0]); acc[2][1] = mfma16(a0, b1, acc[2][1]);
    acc[2][2] = mfma16(a0, b2, acc[2][2]); acc[2][3] = mfma16(a0, b3, acc[2][3]);
    acc[3][0] = mfma16(a1, b0, acc[3][0]); acc[3][1] = mfma16(a1, b1, acc[3][1]);
    acc[3][2] = mfma16(a1, b2, acc[3][2]); acc[3][3] = mfma16(a1, b3, acc[3][3]);
    __builtin_amdgcn_s_setprio(0);
    // RACE FIX: lgkmcnt(0) pins all LDS reads of buffer BUF retired before
    // the release barrier (next tile DMA-overwrites a rotated buffer).
    if (hn2)
      asm volatile("s_waitcnt vmcnt(6) lgkmcnt(0)" ::: "memory");
    else
      asm volatile("s_waitcnt vmcnt(0) lgkmcnt(0)" ::: "memory");
    __builtin_amdgcn_s_barrier(); asm volatile("" ::: "memory");
  };

#pragma unroll 1
  for (int kt = 0; kt < 30; kt += 3) {
    tile(kt,     IC<0>{});
    tile(kt + 1, IC<1>{});
    tile(kt + 2, IC<2>{});
  }
  tile(30, IC<0>{});
  tile(31, IC<1>{});

  float bv[4];
#pragma unroll
  for (int ni = 0; ni < 4; ++ni) bv[ni] = bias[n0 + wc * 64 + ni * 16 + l15];

  if (outmode == 2) {
    const int b = m0 >> 11;
    const int tbase = (m0 & 2047) + wr * 64 + lhi * 4;
#pragma unroll
    for (int mi = 0; mi < 4; ++mi) {
#pragma unroll
      for (int ni = 0; ni < 4; ++ni) {
        int n = n0 + wc * 64 + ni * 16 + l15;
        ushort4 pk;
        pk.x = f2bf(acc[mi][ni][0] + bv[ni]);
        pk.y = f2bf(acc[mi][ni][1] + bv[ni]);
        pk.z = f2bf(acc[mi][ni][2] + bv[ni]);
        pk.w = f2bf(acc[mi][ni][3] + bv[ni]);
        *(ushort4*)((u16*)Cout + (size_t)(b * 2048 + n) * T_ + tbase +
                    mi * 16) = pk;
      }
    }
  } else {
#pragma unroll
    for (int mi = 0; mi < 4; ++mi) {
#pragma unroll
      for (int ni = 0; ni < 4; ++ni) {
        int n = n0 + wc * 64 + ni * 16 + l15;
#pragma unroll
        for (int r = 0; r < 4; ++r) {
          int m = m0 + wr * 64 + mi * 16 + lhi * 4 + r;
          float v = (acc[mi][ni][r] + bv[ni]) * oscale;
          if (outmode == 1)
            ((float*)Cout)[(size_t)m * H_ + n] = v;
          else
            ((u16*)Cout)[(size_t)m * H_ + n] = f2bf(v);
        }
      }
    }
  }
}

template <int OUTMODE>
__global__ __launch_bounds__(512, 1) void gemm256_bt_k(
    const u16* __restrict__ A, const u16* __restrict__ Bm,
    const float* __restrict__ bias, void* __restrict__ Cout, float oscale) {
  gemm256_core(A, Bm, bias, Cout, blockIdx.x, OUTMODE, oscale);
}

// ------------------------------------------------------------ flash attention
// R18 final: dual-state single staging stream, counted vmcnt(8), tree
// reductions, cvt_pk P-pack, T13 defer-max, XCD-grouped bh, lgkmcnt(0)
// race fix at the release barrier.
__global__ __launch_bounds__(256, 2) void attn_kernel(
    const u16* __restrict__ Q, const u16* __restrict__ K,
    const u16* __restrict__ Vt, u16* __restrict__ ctx) {
  __shared__ u16 Ks[2][64 * 128];    // [key][d], 256B rows, swizzled
  __shared__ u16 Vs[2][128 * 64];    // [d][key], 128B rows, swizzled
  __shared__ u16 Ps[4][1024];        // per-wave P^T, swizzled [slot][q][8]

  const int tid = threadIdx.x, wave = tid >> 6, lane = tid & 63;
  const int l15 = lane & 15, lhi = lane >> 4;

  const int bid = blockIdx.x;
  const int xcd = bid & 7, idx = bid >> 3;
  const int bh = xcd * 4 + (idx & 3);       // 4 (b,h) pairs per XCD
  const int qj = idx >> 2;                  // 0..15
  const int qi = (qj < 8) ? qj : 23 - qj;   // complement remap
  const int b = bh >> 4, h = bh & 15;
  const int qb0 = qi, qb1 = 31 - qi;        // qb0 < qb1 always

  const float THR = 11.5f;                  // 8 nats in log2 units
  const float NI  = -__builtin_inff();

  auto stage = [&](auto bufc, int kv0) {
    constexpr int BUF = decltype(bufc)::value;
#pragma unroll
    for (int is = 0; is < 4; ++is) {
      {  // K tile: 64 rows x 256B
        int o_ = is * 4096 + tid * 16;
        int row = o_ >> 8;
        int sw = o_ ^ (((o_ >> 8) & 7) << 4);
        int c8 = (sw >> 4) & 15;
        gload_lds16(K + (size_t)(b * T_ + kv0 + row) * H_ + h * HD_ + c8 * 8,
                    &Ks[BUF][0] + (is * 2048 + wave * 512));
      }
      {  // Vt tile: 128 rows x 128B
        int o_ = is * 4096 + tid * 16;
        int row = o_ >> 7;
        int sw = o_ ^ (((o_ >> 7) & 7) << 4);
        int t8 = (sw >> 4) & 7;
        gload_lds16(Vt + (size_t)(bh * HD_ + row) * T_ + kv0 + t8 * 8,
                    &Vs[BUF][0] + (is * 4096 / 2 + wave * 512));
      }
    }
  };

  // preload both q-tiles' fragments (prologue vmcnt(0) covers them)
  bf16x8 qc0[4], qc1[4];
  {
    const u16* q0p =
        Q + (size_t)(b * T_ + qb0 * 64 + wave * 16 + l15) * H_ + h * HD_ + lhi * 8;
    const u16* q1p =
        Q + (size_t)(b * T_ + qb1 * 64 + wave * 16 + l15) * H_ + h * HD_ + lhi * 8;
#pragma unroll
    for (int kk = 0; kk < 4; ++kk) {
      qc0[kk] = *(const bf16x8*)(q0p + kk * 32);
      qc1[kk] = *(const bf16x8*)(q1p + kk * 32);
    }
  }

  f32x4 o0[8] = {}, o1[8] = {};
  float m20 = NI, lr0 = 0.f, m21 = NI, lr1 = 0.f;

  auto comp = [&](f32x4 (&o)[8], float& m2, float& lr, bf16x8 (&qf)[4],
                  int q0, bool diag, int kv0, auto bufc) {
    constexpr int BUF = decltype(bufc)::value;
    const int qrow = q0 + l15;

    f32x4 sv[4];
    __builtin_amdgcn_s_setprio(1);
#pragma unroll
    for (int kt = 0; kt < 4; ++kt) {
      f32x4 sacc = {0.f, 0.f, 0.f, 0.f};
#pragma unroll
      for (int kk = 0; kk < 4; ++kk) {
        int row = kt * 16 + l15;
        int ob = (row * 256 + kk * 64 + lhi * 16) ^ ((row & 7) << 4);
        bf16x8 kf = *(const bf16x8*)((const char*)&Ks[BUF][0] + ob);
        sacc = mfma16(kf, qf[kk], sacc);
      }
      sv[kt] = sacc;
    }
    __builtin_amdgcn_s_setprio(0);

    float pmax2;
    {
      float pm[4];
      if (diag) {
#pragma unroll
        for (int kt = 0; kt < 4; ++kt) {
          int key0 = kv0 + kt * 16 + lhi * 4;
#pragma unroll
          for (int r = 0; r < 4; ++r)
            sv[kt][r] = (key0 + r <= qrow) ? sv[kt][r] : NI;
          pm[kt] = fmaxf(fmaxf(sv[kt][0], sv[kt][1]),
                         fmaxf(sv[kt][2], sv[kt][3]));
        }
      } else {
#pragma unroll
        for (int kt = 0; kt < 4; ++kt)
          pm[kt] = fmaxf(fmaxf(sv[kt][0], sv[kt][1]),
                         fmaxf(sv[kt][2], sv[kt][3]));
      }
      pmax2 = fmaxf(fmaxf(pm[0], pm[1]), fmaxf(pm[2], pm[3]));
    }
    pmax2 = fmaxf(pmax2, __shfl_xor(pmax2, 16));
    pmax2 = fmaxf(pmax2, __shfl_xor(pmax2, 32));

    if (__any(pmax2 - m2 > THR)) {
      float mn = fmaxf(m2, pmax2);
      float al = exp2f(m2 - mn);
      m2 = mn;
      lr *= al;
      float alo[4];
#pragma unroll
      for (int r = 0; r < 4; ++r) alo[r] = __shfl(al, lhi * 4 + r);
#pragma unroll
      for (int dt = 0; dt < 8; ++dt)
#pragma unroll
        for (int r = 0; r < 4; ++r) o[dt][r] *= alo[r];
    }

    float rsk[4];
#pragma unroll
    for (int kt = 0; kt < 4; ++kt) {
#pragma unroll
      for (int r = 0; r < 4; ++r) sv[kt][r] = exp2f(sv[kt][r] - m2);
      rsk[kt] = (sv[kt][0] + sv[kt][1]) + (sv[kt][2] + sv[kt][3]);
    }
    float rs = (rsk[0] + rsk[1]) + (rsk[2] + rsk[3]);
    rs += __shfl_xor(rs, 16);
    rs += __shfl_xor(rs, 32);
    lr += rs;

#pragma unroll
    for (int kt = 0; kt < 4; ++kt) {
      int slot = kt * 2 + (lhi >> 1);
      uint2 pk;
      pk.x = cvtpk(sv[kt][0], sv[kt][1]);
      pk.y = cvtpk(sv[kt][2], sv[kt][3]);
      *(uint2*)&Ps[wave][slot * 128 + ((l15 * 8) ^ ((slot & 7) << 3)) +
                         (lhi & 1) * 4] = pk;
    }
    asm volatile("" ::: "memory");

    __builtin_amdgcn_s_setprio(1);
#pragma unroll
    for (int ks = 0; ks < 2; ++ks) {
      int slot = ks * 4 + lhi;
      bf16x8 pf = *(const bf16x8*)&Ps[wave][slot * 128 +
                                            ((l15 * 8) ^ ((slot & 7) << 3))];
#pragma unroll
      for (int dt = 0; dt < 8; ++dt) {
        int row = dt * 16 + l15;
        int ob = (row * 128 + ks * 64 + lhi * 16) ^ ((row & 7) << 4);
        bf16x8 vf = *(const bf16x8*)((const char*)&Vs[BUF][0] + ob);
        o[dt] = mfma16(pf, vf, o[dt]);
      }
    }
    __builtin_amdgcn_s_setprio(0);
    asm volatile("" ::: "memory");
  };

  auto flushout = [&](f32x4 (&o)[8], float lr, int qtile) {
    float invo[4];
    float inv = 1.0f / lr;
#pragma unroll
    for (int r = 0; r < 4; ++r) invo[r] = __shfl(inv, lhi * 4 + r);
    int q0 = qtile * 64 + wave * 16;
#pragma unroll
    for (int dt = 0; dt < 8; ++dt)
#pragma unroll
      for (int r = 0; r < 4; ++r)
        ctx[(size_t)(b * T_ + q0 + lhi * 4 + r) * H_ + h * HD_ + dt * 16 +
            l15] = f2bf(o[dt][r] * invo[r]);
  };

  stage(IC<0>{}, 0);
  asm volatile("s_waitcnt vmcnt(0)" ::: "memory");
  __builtin_amdgcn_s_barrier();
  asm volatile("" ::: "memory");

  auto body = [&](int t, auto bufc) {
    constexpr int BUF = decltype(bufc)::value;
    if (t < qb1) stage(IC<BUF ^ 1>{}, (t + 1) * 64);
    if (t < qb1)
      asm volatile("s_waitcnt vmcnt(8)" ::: "memory");
    else
      asm volatile("s_waitcnt vmcnt(0)" ::: "memory");
    __builtin_amdgcn_s_barrier();
    asm volatile("" ::: "memory");

    const int kv0 = t * 64;
    comp(o1, m21, lr1, qc1, qb1 * 64 + wave * 16, t == qb1, kv0, bufc);
    if (t <= qb0)
      comp(o0, m20, lr0, qc0, qb0 * 64 + wave * 16, t == qb0, kv0, bufc);

    // RACE FIX: pin all LDS reads of buffer BUF retired before the release
    // barrier (next body's stage DMAs overwrite BUF).
    asm volatile("s_waitcnt lgkmcnt(0)" ::: "memory");
    __builtin_amdgcn_s_barrier();
    asm volatile("" ::: "memory");
  };

#pragma unroll 1
  for (int t2 = 0; t2 + 1 <= qb1; t2 += 2) {
    body(t2, IC<0>{});
    body(t2 + 1, IC<1>{});
  }
  if ((qb1 & 1) == 0) body(qb1, IC<0>{});

  flushout(o0, lr0, qb0);
  flushout(o1, lr1, qb1);
}

// ------------------------------------------------------------------- launcher
extern "C" void kernel_launch(void* const* d_in, const int* in_sizes, int n_in,
                              void* d_out, int out_size, void* d_ws,
                              size_t ws_size, hipStream_t stream) {
  const float* x  = (const float*)d_in[0];
  const float* wq = (const float*)d_in[1];
  const float* bq = (const float*)d_in[2];
  const float* wk = (const float*)d_in[3];
  const float* bk = (const float*)d_in[4];
  const float* wv = (const float*)d_in[5];
  const float* bv = (const float*)d_in[6];
  const float* wo = (const float*)d_in[7];
  const float* bo = (const float*)d_in[8];

  char* ws = (char*)d_ws;
  constexpr size_t SZ_X = (size_t)M_ * H_ * 2;  // 16.8 MB (bf16 activation)
  constexpr size_t SZ_W = (size_t)H_ * H_ * 2;  // 8.4 MB (bf16 weight)
  u16* xb  = (u16*)(ws);
  u16* wqb = (u16*)(ws + SZ_X);
  u16* wkb = (u16*)(ws + SZ_X + 1 * SZ_W);
  u16* wvb = (u16*)(ws + SZ_X + 2 * SZ_W);
  u16* wob = (u16*)(ws + SZ_X + 3 * SZ_W);
  u16* Qb  = (u16*)(ws + 1 * SZ_X + 4 * SZ_W);
  u16* Kb  = (u16*)(ws + 2 * SZ_X + 4 * SZ_W);
  u16* Vtb = (u16*)(ws + 3 * SZ_X + 4 * SZ_W);  // V^T written by gemm256<2>
  u16* ctx = xb;  // xb is dead after the QKV GEMMs

  // fused fp32->bf16: x + 4 weights, one dispatch (dsts contiguous in ws)
  cvt5_kernel<<<12288, 512, 0, stream>>>((const float4*)x, (const float4*)wq,
                                         (const float4*)wk, (const float4*)wv,
                                         (const float4*)wo, (ushort4*)ws);

  // QKV projections: 256x128-tile 4-phase triple-buffered GEMMs (VALU-diet).
  // Q pre-scaled by C1_ (attn consumes log2-domain scores).
  gemm256_bt_k<0><<<256, 512, 0, stream>>>(xb, wqb, bq, Qb, C1_);
  gemm256_bt_k<0><<<256, 512, 0, stream>>>(xb, wkb, bk, Kb, 1.0f);
  gemm256_bt_k<2><<<256, 512, 0, stream>>>(xb, wvb, bv, Vtb, 1.0f);

  // dual-state paired causal flash attention: 512 blocks x 256 threads
  attn_kernel<<<512, 256, 0, stream>>>(Qb, Kb, Vtb, ctx);

  gemm256_bt_k<1><<<256, 512, 0, stream>>>(ctx, wob, bo, d_out, 1.0f);
}